// Round 2
// baseline (47.827 us; speedup 1.0000x reference)
//
#include <hip/hip_runtime.h>

// Problem constants (fixed by setup_inputs): lfi [B,A,H,W,C], f_maps [B,H,W,F]
#define BB 4
#define AA 9
#define HH 256
#define WW 256
#define CC 9
#define FF 64

// ---------------------------------------------------------------------------
// Stage 1 (fused, disjoint block roles):
//  blocks [0, 1024):   hv[b,w,f] = mean_h f_maps[b,h,w,f]; atomicMax into
//                      maxbuf[b,f] (positive floats -> int-compare is valid)
//  blocks [1024,2048): m[b,h,w] = mean_{a,c} lfi[b,a,h,w,c]
// ---------------------------------------------------------------------------
__global__ __launch_bounds__(256) void k_stage1(const float* __restrict__ fm,
                                                const float* __restrict__ lfi,
                                                float* __restrict__ hv,
                                                int* __restrict__ maxbuf,
                                                float* __restrict__ m) {
    if (blockIdx.x < BB * WW) {
        // ---- hv role: block per (b,w), float4 loads, 16 h-lanes x 16 f4 ----
        const int blk = blockIdx.x;
        const int b = blk >> 8;  // WW == 256
        const int w = blk & 255;
        const int f4 = threadIdx.x & 15;   // float4 index along F (F/4 == 16)
        const int hl = threadIdx.x >> 4;   // 0..15

        const float4* base =
            (const float4*)fm + (((size_t)b * HH) * WW + w) * (FF / 4) + f4;
        float4 acc = make_float4(0.f, 0.f, 0.f, 0.f);
#pragma unroll
        for (int h = hl; h < HH; h += 16) {
            float4 v = base[(size_t)h * WW * (FF / 4)];
            acc.x += v.x; acc.y += v.y; acc.z += v.z; acc.w += v.w;
        }
        __shared__ float sm[16 * FF];  // [hl][f]
        ((float4*)sm)[hl * 16 + f4] = acc;
        __syncthreads();
        if (threadIdx.x < FF) {
            const int f = threadIdx.x;
            float t = 0.f;
#pragma unroll
            for (int j = 0; j < 16; ++j) t += sm[j * FF + f];
            t *= (1.0f / HH);
            hv[(size_t)blk * FF + f] = t;
            atomicMax(maxbuf + b * FF + f, __float_as_int(t));
        }
    } else {
        // ---- m role: one thread per (b,h,w), 81-element unrolled reduce ----
        const int gid = (blockIdx.x - BB * WW) * 256 + threadIdx.x;
        const int b = gid >> 16;  // HH*WW == 65536
        const int hw = gid & 65535;

        const size_t astride = (size_t)HH * WW * CC;  // 589824
        const float* base = lfi + (size_t)b * AA * astride + (size_t)hw * CC;

        float s = 0.f;
#pragma unroll
        for (int a = 0; a < AA; ++a) {
            const float* p = base + (size_t)a * astride;
#pragma unroll
            for (int c = 0; c < CC; ++c) s += p[c];
        }
        m[gid] = s * (1.0f / (AA * CC));
    }
}

// ---------------------------------------------------------------------------
// Stage 2: out[b,h,w,f] = m[b,h,w] * hv[b,h,f] / max[b,f]
// One thread per float4 along f; contiguous 16B/lane stores.
// ---------------------------------------------------------------------------
__global__ __launch_bounds__(256) void k_out(const float* __restrict__ m,
                                             const float* __restrict__ hv,
                                             const int* __restrict__ maxbuf,
                                             float4* __restrict__ out) {
    const int idx = blockIdx.x * 256 + threadIdx.x;  // over B*H*W*F/4
    const int f4 = idx & 15;                         // FF/4 == 16
    const int rest = idx >> 4;                       // b*HH*WW + h*WW + w
    const int h = (rest >> 8) & 255;
    const int b = rest >> 16;

    const float mv = m[rest];
    const float4 hv4 = ((const float4*)hv)[((size_t)(b * HH + h)) * (FF / 4) + f4];
    const int4 mx4 = ((const int4*)maxbuf)[b * (FF / 4) + f4];

    float4 o;
    o.x = mv * hv4.x / __int_as_float(mx4.x);
    o.y = mv * hv4.y / __int_as_float(mx4.y);
    o.z = mv * hv4.z / __int_as_float(mx4.z);
    o.w = mv * hv4.w / __int_as_float(mx4.w);
    out[idx] = o;
}

extern "C" void kernel_launch(void* const* d_in, const int* in_sizes, int n_in,
                              void* d_out, int out_size, void* d_ws, size_t ws_size,
                              hipStream_t stream) {
    const float* lfi = (const float*)d_in[0];  // [B,A,H,W,C] f32
    const float* fm  = (const float*)d_in[1];  // [B,H,W,F]   f32
    float* out = (float*)d_out;                // [B,H,W,F]   f32

    // Workspace layout
    char* ws = (char*)d_ws;
    float* hv  = (float*)ws;                                      // 65536 f
    int*   mxb = (int*)(ws + (size_t)BB * WW * FF * 4);           // 256 i
    float* m   = (float*)(ws + (size_t)BB * WW * FF * 4 + 1024);  // 262144 f

    // 0) zero the atomic-max buffer (int 0 < any positive float's bits)
    hipMemsetAsync(mxb, 0, BB * FF * sizeof(int), stream);
    // 1) fused column-mean(+max) of f_maps and angular mean of lfi
    k_stage1<<<BB * WW + (BB * HH * WW) / 256, 256, 0, stream>>>(fm, lfi, hv, mxb, m);
    // 2) broadcast-multiply into out
    k_out<<<(BB * HH * WW * FF / 4) / 256, 256, 0, stream>>>(m, hv, mxb, (float4*)out);
}